// Round 13
// baseline (116.805 us; speedup 1.0000x reference)
//
#include <hip/hip_runtime.h>

typedef _Float16 f16;
typedef _Float16 f16x2 __attribute__((ext_vector_type(2)));
typedef _Float16 f16x4 __attribute__((ext_vector_type(4)));
typedef _Float16 f16x8 __attribute__((ext_vector_type(8)));
typedef float f32x4 __attribute__((ext_vector_type(4)));

#define I_DIM 320
#define J_DIM 320
#define C_DIM 128
#define NROWS (I_DIM * J_DIM)   // 102400
#define LOG2E 1.44269504f

__device__ inline float pkrtz(float a, float b) {
    return __builtin_bit_cast(float, __builtin_amdgcn_cvt_pkrtz(a, b));  // v_cvt_pkrtz_f16_f32
}

// ---------------- K0: weight prep (f32 -> f16, MFMA B-fragment order) ------
// Wq additionally scaled by LOG2E so QK^T lands directly in exp2 domain.
__global__ __launch_bounds__(256) void prep_kernel(const float* __restrict__ Wq,
                                                   const float* __restrict__ Wk,
                                                   const float* __restrict__ Wv,
                                                   const float* __restrict__ Wg,
                                                   const float* __restrict__ Wo,
                                                   f16* __restrict__ Wfrag) {
    int f = blockIdx.x * 256 + threadIdx.x;           // < 5*16384
    int j = f & 7, lane = (f >> 3) & 63, n = (f >> 9) & 7;
    int ks = (f >> 12) & 3, w = f >> 14;
    int gq = lane >> 4, r16 = lane & 15;
    const float* W = (w == 0) ? Wq : (w == 1) ? Wk : (w == 2) ? Wv : (w == 3) ? Wg : Wo;
    float val = W[(size_t)(ks * 32 + gq * 8 + j) * 128 + n * 16 + r16];
    if (w == 0) val *= LOG2E;
    Wfrag[f] = (f16)val;
}

// ---------------- K1: LayerNorm (f32 -> f16) — unchanged ----------------
__global__ __launch_bounds__(256) void ln_kernel(const float* __restrict__ z,
                                                 const float* __restrict__ scale,
                                                 const float* __restrict__ bias,
                                                 f16* __restrict__ zn) {
    int wave = threadIdx.x >> 6;
    int lane = threadIdx.x & 63;
    int row = blockIdx.x * 4 + wave;
    const float* zr = z + (size_t)row * C_DIM;
    float2 x = *(const float2*)(zr + lane * 2);
    float s = x.x + x.y;
    float sq = x.x * x.x + x.y * x.y;
    #pragma unroll
    for (int o = 32; o; o >>= 1) {
        s  += __shfl_xor(s, o);
        sq += __shfl_xor(sq, o);
    }
    float mu = s * (1.0f / 128.0f);
    float var = sq * (1.0f / 128.0f) - mu * mu;
    float rs = rsqrtf(var + 1e-5f);
    int c0 = lane * 2;
    float y0 = (x.x - mu) * rs * scale[c0] + bias[c0];
    float y1 = (x.y - mu) * rs * scale[c0 + 1] + bias[c0 + 1];
    f16x2 o2 = {(f16)y0, (f16)y1};
    *(f16x2*)(zn + (size_t)row * C_DIM + c0) = o2;
}

// ---------------- K2: fused QKVG-projection + attention per (i,h) ----------
// 640 threads (10 waves), 2 q-tiles per wave. Q^T projected directly into
// registers via operand-swapped MFMA (no LDS bounce); Ksh columns stored with
// the matching sigma' slot relabel; V^T sigma-relabeled (r10-proven); mask via
// MFMA C-operand; softmax denominator via ones-MFMA.
__global__ __launch_bounds__(640, 5) void attn_mega(const f16* __restrict__ zn,
                                                    const f16* __restrict__ Wfrag,
                                                    const float* __restrict__ bg,
                                                    const int* __restrict__ z_mask,
                                                    f16* __restrict__ gwa) {
    __shared__ f16 Ksh[320][40];    // cols sigma'-relabeled: pos (r>>2)*8+(r&3)+4n
    __shared__ f16 Vt[32][328];     // sigma-ordered cols (r10)
    __shared__ float mbs[320];      // log2-domain mask bias (MFMA C-init)

    int bid = blockIdx.x;
    int xcd = bid & 7, idx = bid >> 3;
    int i = xcd * 40 + (idx >> 2);
    int h = idx & 3;
    size_t zbase = (size_t)i * (J_DIM * C_DIM);
    size_t gbase = zbase + h * 32;

    int wave = threadIdx.x >> 6;
    int lane = threadIdx.x & 63;
    int gq = lane >> 4, r16 = lane & 15;

    const f16* wfq = Wfrag;
    const f16* wfk = Wfrag + 16384;
    const f16* wfv = Wfrag + 32768;
    const f16* wfg = Wfrag + 49152;

    for (int t = threadIdx.x; t < 320; t += 640)
        mbs[t] = z_mask[i * J_DIM + t] ? -12.0f : -60000.0f;

    // Phase B: project K and V head-slices into LDS (2 row-tiles per wave)
    for (int rt = wave; rt < 20; rt += 10) {
        f16x8 a[4];
        #pragma unroll
        for (int ks = 0; ks < 4; ++ks)
            a[ks] = *(const f16x8*)(zn + zbase + (size_t)(rt * 16 + r16) * C_DIM + ks * 32 + gq * 8);
        f32x4 kacc[2] = {}, vacc[2] = {};
        #pragma unroll
        for (int ks = 0; ks < 4; ++ks) {
            #pragma unroll
            for (int n = 0; n < 2; ++n) {
                f16x8 bk = *(const f16x8*)(wfk + (ks * 8 + 2 * h + n) * 512 + lane * 8);
                kacc[n] = __builtin_amdgcn_mfma_f32_16x16x32_f16(a[ks], bk, kacc[n], 0, 0, 0);
                f16x8 bv = *(const f16x8*)(wfv + (ks * 8 + 2 * h + n) * 512 + lane * 8);
                vacc[n] = __builtin_amdgcn_mfma_f32_16x16x32_f16(a[ks], bv, vacc[n], 0, 0, 0);
            }
        }
        // K: sigma'-relabeled column position. V^T: sigma-relabeled column base.
        int kcol = (r16 >> 2) * 8 + (r16 & 3);          // + 4n below
        int colbase = (rt >> 1) * 32 + gq * 8 + (rt & 1) * 4;
        #pragma unroll
        for (int n = 0; n < 2; ++n) {
            #pragma unroll
            for (int rr = 0; rr < 4; ++rr)
                Ksh[rt * 16 + gq * 4 + rr][kcol + 4 * n] = (f16)kacc[n][rr];
            f16x4 vp = {(f16)vacc[n][0], (f16)vacc[n][1], (f16)vacc[n][2], (f16)vacc[n][3]};
            *(f16x4*)(&Vt[n * 16 + r16][colbase]) = vp;
        }
    }
    __syncthreads();

    // Phase C: Q^T directly into registers (operand-swapped MFMA, no LDS)
    // qacc'[n][rr] = Q[q=r16][dh = n*16 + 4*gq + rr]
    f16x8 qa[2];
    #pragma unroll
    for (int u = 0; u < 2; ++u) {
        int qt = u * 10 + wave;
        f16x8 a[4];
        #pragma unroll
        for (int ks = 0; ks < 4; ++ks)
            a[ks] = *(const f16x8*)(zn + zbase + (size_t)(qt * 16 + r16) * C_DIM + ks * 32 + gq * 8);
        f32x4 qacc[2] = {};
        #pragma unroll
        for (int ks = 0; ks < 4; ++ks) {
            #pragma unroll
            for (int n = 0; n < 2; ++n) {
                f16x8 bq = *(const f16x8*)(wfq + (ks * 8 + 2 * h + n) * 512 + lane * 8);
                qacc[n] = __builtin_amdgcn_mfma_f32_16x16x32_f16(bq, a[ks], qacc[n], 0, 0, 0);
            }
        }
        union { float f[4]; f16x8 v; } qu;
        qu.f[0] = pkrtz(qacc[0][0], qacc[0][1]);
        qu.f[1] = pkrtz(qacc[0][2], qacc[0][3]);
        qu.f[2] = pkrtz(qacc[1][0], qacc[1][1]);
        qu.f[3] = pkrtz(qacc[1][2], qacc[1][3]);
        qa[u] = qu.v;
    }

    // Phase D: main K loop — 32 keys/iter, both q-tiles share each read.
    const f16x8 ones = {(f16)1, (f16)1, (f16)1, (f16)1, (f16)1, (f16)1, (f16)1, (f16)1};
    f32x4 wa[2][2] = {};
    f32x4 wa2[2] = {};

    for (int kc = 0; kc < 10; ++kc) {
        f16x8 kb0 = *(const f16x8*)(&Ksh[kc * 32 + r16][gq * 8]);
        f16x8 kb1 = *(const f16x8*)(&Ksh[kc * 32 + 16 + r16][gq * 8]);
        f32x4 mk0 = *(const f32x4*)(&mbs[kc * 32 + 4 * gq]);
        f32x4 mk1 = *(const f32x4*)(&mbs[kc * 32 + 16 + 4 * gq]);
        f16x8 vb0 = *(const f16x8*)(&Vt[r16][kc * 32 + gq * 8]);
        f16x8 vb1 = *(const f16x8*)(&Vt[16 + r16][kc * 32 + gq * 8]);
        #pragma unroll
        for (int u = 0; u < 2; ++u) {
            // S^T + mask, exp2 domain (Wq pre-scaled by LOG2E)
            f32x4 sc0 = __builtin_amdgcn_mfma_f32_16x16x32_f16(kb0, qa[u], mk0, 0, 0, 0);
            f32x4 sc1 = __builtin_amdgcn_mfma_f32_16x16x32_f16(kb1, qa[u], mk1, 0, 0, 0);
            float p0[4], p1[4];
            #pragma unroll
            for (int r = 0; r < 4; ++r) {
                p0[r] = __builtin_amdgcn_exp2f(sc0[r]);
                p1[r] = __builtin_amdgcn_exp2f(sc1[r]);
            }
            union { float f[4]; f16x8 v; } pu;
            pu.f[0] = pkrtz(p0[0], p0[1]);
            pu.f[1] = pkrtz(p0[2], p0[3]);
            pu.f[2] = pkrtz(p1[0], p1[1]);
            pu.f[3] = pkrtz(p1[2], p1[3]);
            wa[u][0] = __builtin_amdgcn_mfma_f32_16x16x32_f16(pu.v, vb0, wa[u][0], 0, 0, 0);
            wa[u][1] = __builtin_amdgcn_mfma_f32_16x16x32_f16(pu.v, vb1, wa[u][1], 0, 0, 0);
            wa2[u]   = __builtin_amdgcn_mfma_f32_16x16x32_f16(pu.v, ones, wa2[u], 0, 0, 0);
        }
    }

    // Epilogue: deferred g-projection, gate, normalize (rinv lane-local), store
    float bgv0 = bg[h * 32 + r16];
    float bgv1 = bg[h * 32 + 16 + r16];
    #pragma unroll
    for (int u = 0; u < 2; ++u) {
        int qt = u * 10 + wave;
        float rinv[4];
        #pragma unroll
        for (int r = 0; r < 4; ++r)
            rinv[r] = 1.0f / wa2[u][r];
        f16x8 a[4];
        #pragma unroll
        for (int ks = 0; ks < 4; ++ks)
            a[ks] = *(const f16x8*)(zn + zbase + (size_t)(qt * 16 + r16) * C_DIM + ks * 32 + gq * 8);
        f32x4 gacc[2] = {};
        #pragma unroll
        for (int ks = 0; ks < 4; ++ks) {
            #pragma unroll
            for (int n = 0; n < 2; ++n) {
                f16x8 bgf = *(const f16x8*)(wfg + (ks * 8 + 2 * h + n) * 512 + lane * 8);
                gacc[n] = __builtin_amdgcn_mfma_f32_16x16x32_f16(a[ks], bgf, gacc[n], 0, 0, 0);
            }
        }
        #pragma unroll
        for (int n = 0; n < 2; ++n) {
            float bgn = n ? bgv1 : bgv0;
            #pragma unroll
            for (int r = 0; r < 4; ++r) {
                int jq = qt * 16 + gq * 4 + r;
                int dh = n * 16 + r16;
                float gv = 1.0f / (1.0f + __expf(-(gacc[n][r] + bgn)));
                gwa[gbase + (size_t)jq * C_DIM + dh] = (f16)(gv * wa[u][n][r] * rinv[r]);
            }
        }
    }
}

// ---------------- K4: output projection — unchanged (r4-r12-proven) --------
__global__ __launch_bounds__(256) void out_kernel(const f16* __restrict__ gwa,
                                                  const f16* __restrict__ Wofrag,
                                                  const float* __restrict__ bo,
                                                  const int* __restrict__ z_mask,
                                                  float* __restrict__ out) {
    int wave = threadIdx.x >> 6;
    int lane = threadIdx.x & 63;
    int gq = lane >> 4, r16 = lane & 15;
    int row0 = blockIdx.x * 256 + wave * 64;

    f32x4 acc[4][8] = {};
    #pragma unroll
    for (int ks = 0; ks < 4; ++ks) {
        f16x8 a[4];
        #pragma unroll
        for (int m = 0; m < 4; ++m)
            a[m] = *(const f16x8*)(gwa + (size_t)(row0 + m * 16 + r16) * C_DIM + ks * 32 + gq * 8);
        #pragma unroll
        for (int n = 0; n < 8; ++n) {
            f16x8 b = *(const f16x8*)(Wofrag + (ks * 8 + n) * 512 + lane * 8);
            #pragma unroll
            for (int m = 0; m < 4; ++m)
                acc[m][n] = __builtin_amdgcn_mfma_f32_16x16x32_f16(a[m], b, acc[m][n], 0, 0, 0);
        }
    }
    #pragma unroll
    for (int m = 0; m < 4; ++m) {
        #pragma unroll
        for (int rr = 0; rr < 4; ++rr) {
            int row = row0 + m * 16 + gq * 4 + rr;
            float mk = (float)z_mask[row];
            #pragma unroll
            for (int n = 0; n < 8; ++n) {
                int col = n * 16 + r16;
                out[(size_t)row * C_DIM + col] = (acc[m][n][rr] + bo[col]) * mk;
            }
        }
    }
}

extern "C" void kernel_launch(void* const* d_in, const int* in_sizes, int n_in,
                              void* d_out, int out_size, void* d_ws, size_t ws_size,
                              hipStream_t stream) {
    const float* z        = (const float*)d_in[0];
    const int*   z_mask   = (const int*)d_in[1];
    const float* ln_scale = (const float*)d_in[2];
    const float* ln_bias  = (const float*)d_in[3];
    const float* Wq       = (const float*)d_in[4];
    const float* Wk       = (const float*)d_in[5];
    const float* Wv       = (const float*)d_in[6];
    const float* Wg       = (const float*)d_in[7];
    const float* bg       = (const float*)d_in[8];
    const float* Wo       = (const float*)d_in[9];
    const float* bo       = (const float*)d_in[10];
    float* out = (float*)d_out;

    char* ws = (char*)d_ws;
    const size_t SZ = (size_t)NROWS * C_DIM * sizeof(f16);  // 26,214,400 B
    f16* zn    = (f16*)(ws);           // live through attn_mega
    f16* gwa   = (f16*)(ws + 1 * SZ);  // separate: zn still read while gwa written
    f16* Wfrag = (f16*)(ws + 2 * SZ);  // 163,840 B

    prep_kernel<<<320, 256, 0, stream>>>(Wq, Wk, Wv, Wg, Wo, Wfrag);
    ln_kernel  <<<NROWS / 4, 256, 0, stream>>>(z, ln_scale, ln_bias, zn);
    attn_mega  <<<I_DIM * 4, 640, 0, stream>>>(zn, Wfrag, bg, z_mask, gwa);
    out_kernel <<<NROWS / 256, 256, 0, stream>>>(gwa, Wfrag + 4 * 16384, bo, z_mask, out);
}

// Round 14
// 97.820 us; speedup vs baseline: 1.1941x; 1.1941x over previous
//
#include <hip/hip_runtime.h>

typedef _Float16 f16;
typedef _Float16 f16x2 __attribute__((ext_vector_type(2)));
typedef _Float16 f16x4 __attribute__((ext_vector_type(4)));
typedef _Float16 f16x8 __attribute__((ext_vector_type(8)));
typedef float f32x4 __attribute__((ext_vector_type(4)));

#define I_DIM 320
#define J_DIM 320
#define C_DIM 128
#define NROWS (I_DIM * J_DIM)   // 102400
#define LOG2E 1.44269504f

__device__ inline float pkrtz(float a, float b) {
    return __builtin_bit_cast(float, __builtin_amdgcn_cvt_pkrtz(a, b));  // v_cvt_pkrtz_f16_f32
}

// ---------------- K0: weight prep (f32 -> f16, MFMA B-fragment order) ------
// Wq additionally scaled by LOG2E so QK^T lands directly in exp2 domain.
__global__ __launch_bounds__(256) void prep_kernel(const float* __restrict__ Wq,
                                                   const float* __restrict__ Wk,
                                                   const float* __restrict__ Wv,
                                                   const float* __restrict__ Wg,
                                                   const float* __restrict__ Wo,
                                                   f16* __restrict__ Wfrag) {
    int f = blockIdx.x * 256 + threadIdx.x;           // < 5*16384
    int j = f & 7, lane = (f >> 3) & 63, n = (f >> 9) & 7;
    int ks = (f >> 12) & 3, w = f >> 14;
    int gq = lane >> 4, r16 = lane & 15;
    const float* W = (w == 0) ? Wq : (w == 1) ? Wk : (w == 2) ? Wv : (w == 3) ? Wg : Wo;
    float val = W[(size_t)(ks * 32 + gq * 8 + j) * 128 + n * 16 + r16];
    if (w == 0) val *= LOG2E;
    Wfrag[f] = (f16)val;
}

// ---------------- K1: LayerNorm (f32 -> f16) — unchanged ----------------
__global__ __launch_bounds__(256) void ln_kernel(const float* __restrict__ z,
                                                 const float* __restrict__ scale,
                                                 const float* __restrict__ bias,
                                                 f16* __restrict__ zn) {
    int wave = threadIdx.x >> 6;
    int lane = threadIdx.x & 63;
    int row = blockIdx.x * 4 + wave;
    const float* zr = z + (size_t)row * C_DIM;
    float2 x = *(const float2*)(zr + lane * 2);
    float s = x.x + x.y;
    float sq = x.x * x.x + x.y * x.y;
    #pragma unroll
    for (int o = 32; o; o >>= 1) {
        s  += __shfl_xor(s, o);
        sq += __shfl_xor(sq, o);
    }
    float mu = s * (1.0f / 128.0f);
    float var = sq * (1.0f / 128.0f) - mu * mu;
    float rs = rsqrtf(var + 1e-5f);
    int c0 = lane * 2;
    float y0 = (x.x - mu) * rs * scale[c0] + bias[c0];
    float y1 = (x.y - mu) * rs * scale[c0 + 1] + bias[c0 + 1];
    f16x2 o2 = {(f16)y0, (f16)y1};
    *(f16x2*)(zn + (size_t)row * C_DIM + c0) = o2;
}

// ---------------- K2: fused QKVG-projection + attention per (i,h) ----------
// 256 threads (4 waves), 5 q-tiles per wave (r12 amortization). Q^T projected
// straight to registers via operand-swapped MFMA + sigma'-relabeled Ksh
// (r13-proven); g-projection fused into phase C reusing the same zn A-frags
// (epilogue is pure register math); V^T sigma-relabeled; mask via MFMA
// C-operand; softmax denominator via ones-MFMA.
__global__ __launch_bounds__(256, 3) void attn_mega(const f16* __restrict__ zn,
                                                    const f16* __restrict__ Wfrag,
                                                    const float* __restrict__ bg,
                                                    const int* __restrict__ z_mask,
                                                    f16* __restrict__ gwa) {
    __shared__ f16 Ksh[320][40];    // cols sigma'-relabeled: pos (r>>2)*8+(r&3)+4n
    __shared__ f16 Vt[32][328];     // sigma-ordered cols (r10)
    __shared__ float mbs[320];      // log2-domain mask bias (MFMA C-init)

    int bid = blockIdx.x;
    int xcd = bid & 7, idx = bid >> 3;
    int i = xcd * 40 + (idx >> 2);
    int h = idx & 3;
    size_t zbase = (size_t)i * (J_DIM * C_DIM);
    size_t gbase = zbase + h * 32;

    int wave = threadIdx.x >> 6;
    int lane = threadIdx.x & 63;
    int gq = lane >> 4, r16 = lane & 15;

    const f16* wfq = Wfrag;
    const f16* wfk = Wfrag + 16384;
    const f16* wfv = Wfrag + 32768;
    const f16* wfg = Wfrag + 49152;

    for (int t = threadIdx.x; t < 320; t += 256)
        mbs[t] = z_mask[i * J_DIM + t] ? -12.0f : -60000.0f;

    // Phase B: project K and V head-slices into LDS (5 row-tiles per wave)
    for (int rt = wave; rt < 20; rt += 4) {
        f16x8 a[4];
        #pragma unroll
        for (int ks = 0; ks < 4; ++ks)
            a[ks] = *(const f16x8*)(zn + zbase + (size_t)(rt * 16 + r16) * C_DIM + ks * 32 + gq * 8);
        f32x4 kacc[2] = {}, vacc[2] = {};
        #pragma unroll
        for (int ks = 0; ks < 4; ++ks) {
            #pragma unroll
            for (int n = 0; n < 2; ++n) {
                f16x8 bk = *(const f16x8*)(wfk + (ks * 8 + 2 * h + n) * 512 + lane * 8);
                kacc[n] = __builtin_amdgcn_mfma_f32_16x16x32_f16(a[ks], bk, kacc[n], 0, 0, 0);
                f16x8 bv = *(const f16x8*)(wfv + (ks * 8 + 2 * h + n) * 512 + lane * 8);
                vacc[n] = __builtin_amdgcn_mfma_f32_16x16x32_f16(a[ks], bv, vacc[n], 0, 0, 0);
            }
        }
        // K: sigma'-relabeled column position. V^T: sigma-relabeled column base.
        int kcol = (r16 >> 2) * 8 + (r16 & 3);          // + 4n below
        int colbase = (rt >> 1) * 32 + gq * 8 + (rt & 1) * 4;
        #pragma unroll
        for (int n = 0; n < 2; ++n) {
            #pragma unroll
            for (int rr = 0; rr < 4; ++rr)
                Ksh[rt * 16 + gq * 4 + rr][kcol + 4 * n] = (f16)kacc[n][rr];
            f16x4 vp = {(f16)vacc[n][0], (f16)vacc[n][1], (f16)vacc[n][2], (f16)vacc[n][3]};
            *(f16x4*)(&Vt[n * 16 + r16][colbase]) = vp;
        }
    }
    __syncthreads();

    // Phase C: Q^T -> registers (swapped MFMA) AND g-projection (normal MFMA),
    // both from the SAME zn A-fragments. No LDS bounce, no epilogue reloads.
    f16x8 qa[5];
    f32x4 gacc[5][2] = {};
    #pragma unroll
    for (int u = 0; u < 5; ++u) {
        int qt = u * 4 + wave;
        f16x8 a[4];
        #pragma unroll
        for (int ks = 0; ks < 4; ++ks)
            a[ks] = *(const f16x8*)(zn + zbase + (size_t)(qt * 16 + r16) * C_DIM + ks * 32 + gq * 8);
        f32x4 qacc[2] = {};
        #pragma unroll
        for (int ks = 0; ks < 4; ++ks) {
            #pragma unroll
            for (int n = 0; n < 2; ++n) {
                f16x8 bq = *(const f16x8*)(wfq + (ks * 8 + 2 * h + n) * 512 + lane * 8);
                qacc[n] = __builtin_amdgcn_mfma_f32_16x16x32_f16(bq, a[ks], qacc[n], 0, 0, 0);
                f16x8 bgf = *(const f16x8*)(wfg + (ks * 8 + 2 * h + n) * 512 + lane * 8);
                gacc[u][n] = __builtin_amdgcn_mfma_f32_16x16x32_f16(a[ks], bgf, gacc[u][n], 0, 0, 0);
            }
        }
        union { float f[4]; f16x8 v; } qu;
        qu.f[0] = pkrtz(qacc[0][0], qacc[0][1]);
        qu.f[1] = pkrtz(qacc[0][2], qacc[0][3]);
        qu.f[2] = pkrtz(qacc[1][0], qacc[1][1]);
        qu.f[3] = pkrtz(qacc[1][2], qacc[1][3]);
        qa[u] = qu.v;
    }

    // Phase D: main K loop — 32 keys/iter, all 5 q-tiles share each read.
    const f16x8 ones = {(f16)1, (f16)1, (f16)1, (f16)1, (f16)1, (f16)1, (f16)1, (f16)1};
    f32x4 wa[5][2] = {};
    f32x4 wa2[5] = {};

    #pragma unroll 2
    for (int kc = 0; kc < 10; ++kc) {
        f16x8 kb0 = *(const f16x8*)(&Ksh[kc * 32 + r16][gq * 8]);
        f16x8 kb1 = *(const f16x8*)(&Ksh[kc * 32 + 16 + r16][gq * 8]);
        f32x4 mk0 = *(const f32x4*)(&mbs[kc * 32 + 4 * gq]);
        f32x4 mk1 = *(const f32x4*)(&mbs[kc * 32 + 16 + 4 * gq]);
        f16x8 vb0 = *(const f16x8*)(&Vt[r16][kc * 32 + gq * 8]);
        f16x8 vb1 = *(const f16x8*)(&Vt[16 + r16][kc * 32 + gq * 8]);
        #pragma unroll
        for (int u = 0; u < 5; ++u) {
            // S^T + mask, exp2 domain (Wq pre-scaled by LOG2E)
            f32x4 sc0 = __builtin_amdgcn_mfma_f32_16x16x32_f16(kb0, qa[u], mk0, 0, 0, 0);
            f32x4 sc1 = __builtin_amdgcn_mfma_f32_16x16x32_f16(kb1, qa[u], mk1, 0, 0, 0);
            float p0[4], p1[4];
            #pragma unroll
            for (int r = 0; r < 4; ++r) {
                p0[r] = __builtin_amdgcn_exp2f(sc0[r]);
                p1[r] = __builtin_amdgcn_exp2f(sc1[r]);
            }
            union { float f[4]; f16x8 v; } pu;
            pu.f[0] = pkrtz(p0[0], p0[1]);
            pu.f[1] = pkrtz(p0[2], p0[3]);
            pu.f[2] = pkrtz(p1[0], p1[1]);
            pu.f[3] = pkrtz(p1[2], p1[3]);
            wa[u][0] = __builtin_amdgcn_mfma_f32_16x16x32_f16(pu.v, vb0, wa[u][0], 0, 0, 0);
            wa[u][1] = __builtin_amdgcn_mfma_f32_16x16x32_f16(pu.v, vb1, wa[u][1], 0, 0, 0);
            wa2[u]   = __builtin_amdgcn_mfma_f32_16x16x32_f16(pu.v, ones, wa2[u], 0, 0, 0);
        }
    }

    // Epilogue: pure register math — normalize, gate, store
    float bgv0 = bg[h * 32 + r16];
    float bgv1 = bg[h * 32 + 16 + r16];
    #pragma unroll
    for (int u = 0; u < 5; ++u) {
        int qt = u * 4 + wave;
        float rinv[4];
        #pragma unroll
        for (int r = 0; r < 4; ++r)
            rinv[r] = 1.0f / wa2[u][r];
        #pragma unroll
        for (int n = 0; n < 2; ++n) {
            float bgn = n ? bgv1 : bgv0;
            #pragma unroll
            for (int r = 0; r < 4; ++r) {
                int jq = qt * 16 + gq * 4 + r;
                int dh = n * 16 + r16;
                float gv = 1.0f / (1.0f + __expf(-(gacc[u][n][r] + bgn)));
                gwa[gbase + (size_t)jq * C_DIM + dh] = (f16)(gv * wa[u][n][r] * rinv[r]);
            }
        }
    }
}

// ---------------- K4: output projection — unchanged (r4-r13-proven) --------
__global__ __launch_bounds__(256) void out_kernel(const f16* __restrict__ gwa,
                                                  const f16* __restrict__ Wofrag,
                                                  const float* __restrict__ bo,
                                                  const int* __restrict__ z_mask,
                                                  float* __restrict__ out) {
    int wave = threadIdx.x >> 6;
    int lane = threadIdx.x & 63;
    int gq = lane >> 4, r16 = lane & 15;
    int row0 = blockIdx.x * 256 + wave * 64;

    f32x4 acc[4][8] = {};
    #pragma unroll
    for (int ks = 0; ks < 4; ++ks) {
        f16x8 a[4];
        #pragma unroll
        for (int m = 0; m < 4; ++m)
            a[m] = *(const f16x8*)(gwa + (size_t)(row0 + m * 16 + r16) * C_DIM + ks * 32 + gq * 8);
        #pragma unroll
        for (int n = 0; n < 8; ++n) {
            f16x8 b = *(const f16x8*)(Wofrag + (ks * 8 + n) * 512 + lane * 8);
            #pragma unroll
            for (int m = 0; m < 4; ++m)
                acc[m][n] = __builtin_amdgcn_mfma_f32_16x16x32_f16(a[m], b, acc[m][n], 0, 0, 0);
        }
    }
    #pragma unroll
    for (int m = 0; m < 4; ++m) {
        #pragma unroll
        for (int rr = 0; rr < 4; ++rr) {
            int row = row0 + m * 16 + gq * 4 + rr;
            float mk = (float)z_mask[row];
            #pragma unroll
            for (int n = 0; n < 8; ++n) {
                int col = n * 16 + r16;
                out[(size_t)row * C_DIM + col] = (acc[m][n][rr] + bo[col]) * mk;
            }
        }
    }
}

extern "C" void kernel_launch(void* const* d_in, const int* in_sizes, int n_in,
                              void* d_out, int out_size, void* d_ws, size_t ws_size,
                              hipStream_t stream) {
    const float* z        = (const float*)d_in[0];
    const int*   z_mask   = (const int*)d_in[1];
    const float* ln_scale = (const float*)d_in[2];
    const float* ln_bias  = (const float*)d_in[3];
    const float* Wq       = (const float*)d_in[4];
    const float* Wk       = (const float*)d_in[5];
    const float* Wv       = (const float*)d_in[6];
    const float* Wg       = (const float*)d_in[7];
    const float* bg       = (const float*)d_in[8];
    const float* Wo       = (const float*)d_in[9];
    const float* bo       = (const float*)d_in[10];
    float* out = (float*)d_out;

    char* ws = (char*)d_ws;
    const size_t SZ = (size_t)NROWS * C_DIM * sizeof(f16);  // 26,214,400 B
    f16* zn    = (f16*)(ws);           // live through attn_mega
    f16* gwa   = (f16*)(ws + 1 * SZ);  // separate: zn still read while gwa written
    f16* Wfrag = (f16*)(ws + 2 * SZ);  // 163,840 B

    prep_kernel<<<320, 256, 0, stream>>>(Wq, Wk, Wv, Wg, Wo, Wfrag);
    ln_kernel  <<<NROWS / 4, 256, 0, stream>>>(z, ln_scale, ln_bias, zn);
    attn_mega  <<<I_DIM * 4, 256, 0, stream>>>(zn, Wfrag, bg, z_mask, gwa);
    out_kernel <<<NROWS / 256, 256, 0, stream>>>(gwa, Wfrag + 4 * 16384, bo, z_mask, out);
}